// Round 1
// baseline (3164.042 us; speedup 1.0000x reference)
//
#include <hip/hip_runtime.h>

#define IN_DIM 128
#define HID 128
#define ROWS 16
#define LDC 260  // 256 + 4 pad: breaks same-bank stride, keeps float4 alignment

__global__ __launch_bounds__(256) void deg_kernel(const int* __restrict__ dst,
                                                  float* __restrict__ deg, int E) {
    int e = blockIdx.x * 256 + threadIdx.x;
    if (e < E) atomicAdd(&deg[dst[e]], 1.0f);
}

__global__ __launch_bounds__(256) void norm_kernel(float* __restrict__ deg, int n) {
    int i = blockIdx.x * 256 + threadIdx.x;
    if (i < n) deg[i] = rsqrtf(fmaxf(deg[i], 1.0f));
}

// One edge handled by 32 lanes (4 floats each). agg += h[src]*norm[src]
__global__ __launch_bounds__(256) void scatter_kernel(const float* __restrict__ h,
                                                      const float* __restrict__ norm,
                                                      const int* __restrict__ src,
                                                      const int* __restrict__ dst,
                                                      float* agg, int E) {
    int t = blockIdx.x * 256 + threadIdx.x;
    int e = t >> 5;
    if (e >= E) return;
    int c = (t & 31) << 2;
    int s = src[e];
    int d = dst[e];
    float ns = norm[s];
    const float4 v = *(const float4*)(h + (size_t)s * IN_DIM + c);
    float* p = agg + (size_t)d * IN_DIM + c;
    atomicAdd(p + 0, v.x * ns);
    atomicAdd(p + 1, v.y * ns);
    atomicAdd(p + 2, v.z * ns);
    atomicAdd(p + 3, v.w * ns);
}

// out[n][j] = normalize_row( [h[n], agg[n]*norm[n]] @ W + bias )
// agg and out alias (in-place): all reads happen in the tile-load phase
// before __syncthreads(); each row is owned by exactly one block.
__global__ __launch_bounds__(256) void gemm_kernel(const float* __restrict__ h,
                                                   const float* agg,
                                                   const float* __restrict__ norm,
                                                   const float* __restrict__ W,
                                                   const float* __restrict__ bias,
                                                   float* out, int n) {
    __shared__ float cat[ROWS * LDC];
    const int tid = threadIdx.x;
    const int row0 = blockIdx.x * ROWS;

    // Stage cat tile: 16 rows x 256 floats; 4 float4 loads per thread.
#pragma unroll
    for (int i = 0; i < 4; ++i) {
        int f = tid + i * 256;   // float4 slot 0..1023
        int r = f >> 6;          // row in tile
        int c4 = f & 63;         // float4 col
        int row = row0 + r;
        if (row < n) {
            float4 v;
            if (c4 < 32) {
                v = *(const float4*)(h + (size_t)row * IN_DIM + c4 * 4);
            } else {
                float nr = norm[row];
                float4 a = *(const float4*)(agg + (size_t)row * IN_DIM + (c4 - 32) * 4);
                v = make_float4(a.x * nr, a.y * nr, a.z * nr, a.w * nr);
            }
            *(float4*)(cat + r * LDC + c4 * 4) = v;
        }
    }
    __syncthreads();

    const int r = tid >> 4;            // tile row (16 lanes per row)
    const int jg = (tid & 15) * 8;     // output col base (8 cols per thread)
    const int row = row0 + r;
    if (row >= n) return;

    float acc[8];
#pragma unroll
    for (int i = 0; i < 8; ++i) acc[i] = 0.f;

    const float* crow = cat + r * LDC;
    for (int k = 0; k < 2 * IN_DIM; k += 4) {
        float4 a4 = *(const float4*)(crow + k);   // broadcast ds_read_b128
        const float* wk = W + (size_t)k * HID + jg;
#pragma unroll
        for (int kk = 0; kk < 4; ++kk) {
            float a = (&a4.x)[kk];
            float4 w0 = *(const float4*)(wk + kk * HID);
            float4 w1 = *(const float4*)(wk + kk * HID + 4);
            acc[0] += a * w0.x; acc[1] += a * w0.y;
            acc[2] += a * w0.z; acc[3] += a * w0.w;
            acc[4] += a * w1.x; acc[5] += a * w1.y;
            acc[6] += a * w1.z; acc[7] += a * w1.w;
        }
    }

    float4 b0 = *(const float4*)(bias + jg);
    float4 b1 = *(const float4*)(bias + jg + 4);
    acc[0] += b0.x; acc[1] += b0.y; acc[2] += b0.z; acc[3] += b0.w;
    acc[4] += b1.x; acc[5] += b1.y; acc[6] += b1.z; acc[7] += b1.w;

    float ss = 0.f;
#pragma unroll
    for (int i = 0; i < 8; ++i) ss += acc[i] * acc[i];
    // 16 lanes own one row (aligned groups) -> xor-reduce within group
#pragma unroll
    for (int m = 1; m < 16; m <<= 1) ss += __shfl_xor(ss, m);
    float inv = rsqrtf(ss);

    float4 o0 = make_float4(acc[0] * inv, acc[1] * inv, acc[2] * inv, acc[3] * inv);
    float4 o1 = make_float4(acc[4] * inv, acc[5] * inv, acc[6] * inv, acc[7] * inv);
    float* orow = out + (size_t)row * HID + jg;
    *(float4*)orow = o0;
    *(float4*)(orow + 4) = o1;
}

extern "C" void kernel_launch(void* const* d_in, const int* in_sizes, int n_in,
                              void* d_out, int out_size, void* d_ws, size_t ws_size,
                              hipStream_t stream) {
    const float* h = (const float*)d_in[0];
    const float* W = (const float*)d_in[1];
    const float* bias = (const float*)d_in[2];
    const int* src = (const int*)d_in[3];
    const int* dst = (const int*)d_in[4];
    float* out = (float*)d_out;

    const int n = in_sizes[0] / IN_DIM;   // 100000
    const int E = in_sizes[3];            // 1600000

    float* deg = (float*)d_ws;            // N floats; becomes norm in place

    // zero degree counters and the agg accumulator (aliased onto d_out)
    hipMemsetAsync(deg, 0, (size_t)n * sizeof(float), stream);
    hipMemsetAsync(out, 0, (size_t)n * HID * sizeof(float), stream);

    deg_kernel<<<(E + 255) / 256, 256, 0, stream>>>(dst, deg, E);
    norm_kernel<<<(n + 255) / 256, 256, 0, stream>>>(deg, n);

    int scatter_blocks = (E * 32 + 255) / 256;  // 32 lanes per edge
    scatter_kernel<<<scatter_blocks, 256, 0, stream>>>(h, deg, src, dst, out, E);

    gemm_kernel<<<(n + ROWS - 1) / ROWS, 256, 0, stream>>>(h, out, deg, W, bias, out, n);
}

// Round 2
// 716.003 us; speedup vs baseline: 4.4190x; 4.4190x over previous
//
#include <hip/hip_runtime.h>

#define IN_DIM 128
#define HID 128
#define ROWS 16
#define LDC 260  // 256 + 4 pad

// ---------- degree count (int atomics) ----------
__global__ __launch_bounds__(256) void deg_kernel(const int* __restrict__ dst,
                                                  int* __restrict__ deg, int E) {
    int e = blockIdx.x * 256 + threadIdx.x;
    if (e < E) atomicAdd(&deg[dst[e]], 1);
}

__global__ __launch_bounds__(256) void norm_kernel(const int* __restrict__ deg,
                                                   float* __restrict__ norm, int n) {
    int i = blockIdx.x * 256 + threadIdx.x;
    if (i < n) norm[i] = rsqrtf(fmaxf((float)deg[i], 1.0f));
}

// ---------- exclusive scan of deg -> rowptr (1024 elems / block) ----------
__global__ __launch_bounds__(256) void scan1_kernel(const int* __restrict__ deg,
                                                    int* __restrict__ excl,
                                                    int* __restrict__ bsums, int n) {
    __shared__ int sh[256];
    const int tid = threadIdx.x;
    const int base = blockIdx.x * 1024 + tid * 4;
    int v[4];
#pragma unroll
    for (int j = 0; j < 4; ++j) { int idx = base + j; v[j] = (idx < n) ? deg[idx] : 0; }
    int sum = v[0] + v[1] + v[2] + v[3];
    sh[tid] = sum;
    __syncthreads();
    for (int off = 1; off < 256; off <<= 1) {
        int t = (tid >= off) ? sh[tid - off] : 0;
        __syncthreads();
        sh[tid] += t;
        __syncthreads();
    }
    int run = sh[tid] - sum;  // exclusive prefix of this thread
#pragma unroll
    for (int j = 0; j < 4; ++j) { int idx = base + j; if (idx < n) excl[idx] = run; run += v[j]; }
    if (tid == 255) bsums[blockIdx.x] = sh[255];
}

__global__ __launch_bounds__(256) void scan2_kernel(int* __restrict__ bsums, int nb) {
    __shared__ int sh[256];
    const int tid = threadIdx.x;
    int v = (tid < nb) ? bsums[tid] : 0;
    sh[tid] = v;
    __syncthreads();
    for (int off = 1; off < 256; off <<= 1) {
        int t = (tid >= off) ? sh[tid - off] : 0;
        __syncthreads();
        sh[tid] += t;
        __syncthreads();
    }
    if (tid < nb) bsums[tid] = sh[tid] - v;  // exclusive
}

__global__ __launch_bounds__(256) void scan3_kernel(int* __restrict__ rowptr,
                                                    int* __restrict__ cursor,
                                                    const int* __restrict__ bsums, int n) {
    const int tid = threadIdx.x;
    const int base = blockIdx.x * 1024 + tid * 4;
    const int add = bsums[blockIdx.x];
#pragma unroll
    for (int j = 0; j < 4; ++j) {
        int idx = base + j;
        if (idx < n) { int r = rowptr[idx] + add; rowptr[idx] = r; cursor[idx] = r; }
    }
}

// ---------- bucket edges by dst ----------
__global__ __launch_bounds__(256) void fill_kernel(const int* __restrict__ src,
                                                   const int* __restrict__ dst,
                                                   int* __restrict__ cursor,
                                                   int* __restrict__ sorted_src, int E) {
    int e = blockIdx.x * 256 + threadIdx.x;
    if (e < E) {
        int pos = atomicAdd(&cursor[dst[e]], 1);
        sorted_src[pos] = src[e];
    }
}

// ---------- gather-reduce: one wave (64 lanes) per dst row ----------
__global__ __launch_bounds__(256) void agg_kernel(const float* __restrict__ h,
                                                  const float* __restrict__ norm,
                                                  const int* __restrict__ rowptr,
                                                  const int* __restrict__ sorted_src,
                                                  float* __restrict__ agg, int n, int E) {
    const int wid = (blockIdx.x * 256 + threadIdx.x) >> 6;  // row
    const int lane = threadIdx.x & 63;
    if (wid >= n) return;
    const int start = rowptr[wid];
    const int end = (wid + 1 < n) ? rowptr[wid + 1] : E;

    float ax = 0.f, ay = 0.f;
    const float* hp = h + lane * 2;
    int k = start;
    for (; k + 1 < end; k += 2) {
        int s0 = sorted_src[k], s1 = sorted_src[k + 1];
        float n0 = norm[s0], n1 = norm[s1];
        float2 v0 = *(const float2*)(hp + (size_t)s0 * IN_DIM);
        float2 v1 = *(const float2*)(hp + (size_t)s1 * IN_DIM);
        ax += v0.x * n0 + v1.x * n1;
        ay += v0.y * n0 + v1.y * n1;
    }
    if (k < end) {
        int s0 = sorted_src[k];
        float n0 = norm[s0];
        float2 v0 = *(const float2*)(hp + (size_t)s0 * IN_DIM);
        ax += v0.x * n0;
        ay += v0.y * n0;
    }
    const float nd = norm[wid];
    float2 o = make_float2(ax * nd, ay * nd);
    *(float2*)(agg + (size_t)wid * IN_DIM + lane * 2) = o;
}

// ---------- GEMM + row L2-normalize ----------
// out[n][j] = normalize_row( [h[n], agg[n]] @ W + bias )
// agg and out alias: all reads precede writes (per-block tile staged first).
__global__ __launch_bounds__(256) void gemm_kernel(const float* __restrict__ h,
                                                   const float* agg,
                                                   const float* __restrict__ W,
                                                   const float* __restrict__ bias,
                                                   float* out, int n) {
    __shared__ float cat[ROWS * LDC];
    const int tid = threadIdx.x;
    const int row0 = blockIdx.x * ROWS;

#pragma unroll
    for (int i = 0; i < 4; ++i) {
        int f = tid + i * 256;
        int r = f >> 6;
        int c4 = f & 63;
        int row = row0 + r;
        if (row < n) {
            float4 v;
            if (c4 < 32) v = *(const float4*)(h + (size_t)row * IN_DIM + c4 * 4);
            else         v = *(const float4*)(agg + (size_t)row * IN_DIM + (c4 - 32) * 4);
            *(float4*)(cat + r * LDC + c4 * 4) = v;
        }
    }
    __syncthreads();

    const int r = tid >> 4;
    const int jg = (tid & 15) * 8;
    const int row = row0 + r;
    if (row >= n) return;

    float acc[8];
#pragma unroll
    for (int i = 0; i < 8; ++i) acc[i] = 0.f;

    const float* crow = cat + r * LDC;
    for (int k = 0; k < 2 * IN_DIM; k += 4) {
        float4 a4 = *(const float4*)(crow + k);
        const float* wk = W + (size_t)k * HID + jg;
#pragma unroll
        for (int kk = 0; kk < 4; ++kk) {
            float a = (&a4.x)[kk];
            float4 w0 = *(const float4*)(wk + kk * HID);
            float4 w1 = *(const float4*)(wk + kk * HID + 4);
            acc[0] += a * w0.x; acc[1] += a * w0.y;
            acc[2] += a * w0.z; acc[3] += a * w0.w;
            acc[4] += a * w1.x; acc[5] += a * w1.y;
            acc[6] += a * w1.z; acc[7] += a * w1.w;
        }
    }

    float4 b0 = *(const float4*)(bias + jg);
    float4 b1 = *(const float4*)(bias + jg + 4);
    acc[0] += b0.x; acc[1] += b0.y; acc[2] += b0.z; acc[3] += b0.w;
    acc[4] += b1.x; acc[5] += b1.y; acc[6] += b1.z; acc[7] += b1.w;

    float ss = 0.f;
#pragma unroll
    for (int i = 0; i < 8; ++i) ss += acc[i] * acc[i];
#pragma unroll
    for (int m = 1; m < 16; m <<= 1) ss += __shfl_xor(ss, m);
    float inv = rsqrtf(ss);

    float4 o0 = make_float4(acc[0] * inv, acc[1] * inv, acc[2] * inv, acc[3] * inv);
    float4 o1 = make_float4(acc[4] * inv, acc[5] * inv, acc[6] * inv, acc[7] * inv);
    float* orow = out + (size_t)row * HID + jg;
    *(float4*)orow = o0;
    *(float4*)(orow + 4) = o1;
}

extern "C" void kernel_launch(void* const* d_in, const int* in_sizes, int n_in,
                              void* d_out, int out_size, void* d_ws, size_t ws_size,
                              hipStream_t stream) {
    const float* h = (const float*)d_in[0];
    const float* W = (const float*)d_in[1];
    const float* bias = (const float*)d_in[2];
    const int* src = (const int*)d_in[3];
    const int* dst = (const int*)d_in[4];
    float* out = (float*)d_out;

    const int n = in_sizes[0] / IN_DIM;   // 100000
    const int E = in_sizes[3];            // 1600000

    // workspace layout (4B units): deg[N] | rowptr[N] | cursor[N] | norm[N] | bsums[256] | sorted_src[E]
    int* deg = (int*)d_ws;
    int* rowptr = deg + n;
    int* cursor = rowptr + n;
    float* norm = (float*)(cursor + n);
    int* bsums = (int*)(norm + n);
    int* sorted_src = bsums + 256;

    const int nb = (n + 1023) / 1024;  // 98 scan blocks

    hipMemsetAsync(deg, 0, (size_t)n * sizeof(int), stream);

    deg_kernel<<<(E + 255) / 256, 256, 0, stream>>>(dst, deg, E);
    norm_kernel<<<(n + 255) / 256, 256, 0, stream>>>(deg, norm, n);

    scan1_kernel<<<nb, 256, 0, stream>>>(deg, rowptr, bsums, n);
    scan2_kernel<<<1, 256, 0, stream>>>(bsums, nb);
    scan3_kernel<<<nb, 256, 0, stream>>>(rowptr, cursor, bsums, n);

    fill_kernel<<<(E + 255) / 256, 256, 0, stream>>>(src, dst, cursor, sorted_src, E);

    // one 64-lane wave per row, 4 rows per block
    agg_kernel<<<(n + 3) / 4, 256, 0, stream>>>(h, norm, rowptr, sorted_src, out, n, E);

    gemm_kernel<<<(n + ROWS - 1) / ROWS, 256, 0, stream>>>(h, out, W, bias, out, n);
}

// Round 3
// 531.405 us; speedup vs baseline: 5.9541x; 1.3474x over previous
//
#include <hip/hip_runtime.h>

#define IN_DIM 128
#define HID 128
#define ROWS 32
#define LDC 260  // 256 + 4 pad

// ---------- degree count (int atomics) ----------
__global__ __launch_bounds__(256) void deg_kernel(const int* __restrict__ dst,
                                                  int* __restrict__ deg, int E) {
    int e = blockIdx.x * 256 + threadIdx.x;
    if (e < E) atomicAdd(&deg[dst[e]], 1);
}

__global__ __launch_bounds__(256) void norm_kernel(const int* __restrict__ deg,
                                                   float* __restrict__ norm, int n) {
    int i = blockIdx.x * 256 + threadIdx.x;
    if (i < n) norm[i] = rsqrtf(fmaxf((float)deg[i], 1.0f));
}

// ---------- exclusive scan of deg -> rowptr ----------
__global__ __launch_bounds__(256) void scan1_kernel(const int* __restrict__ deg,
                                                    int* __restrict__ excl,
                                                    int* __restrict__ bsums, int n) {
    __shared__ int sh[256];
    const int tid = threadIdx.x;
    const int base = blockIdx.x * 1024 + tid * 4;
    int v[4];
#pragma unroll
    for (int j = 0; j < 4; ++j) { int idx = base + j; v[j] = (idx < n) ? deg[idx] : 0; }
    int sum = v[0] + v[1] + v[2] + v[3];
    sh[tid] = sum;
    __syncthreads();
    for (int off = 1; off < 256; off <<= 1) {
        int t = (tid >= off) ? sh[tid - off] : 0;
        __syncthreads();
        sh[tid] += t;
        __syncthreads();
    }
    int run = sh[tid] - sum;
#pragma unroll
    for (int j = 0; j < 4; ++j) { int idx = base + j; if (idx < n) excl[idx] = run; run += v[j]; }
    if (tid == 255) bsums[blockIdx.x] = sh[255];
}

__global__ __launch_bounds__(256) void scan2_kernel(int* __restrict__ bsums, int nb) {
    __shared__ int sh[256];
    const int tid = threadIdx.x;
    int v = (tid < nb) ? bsums[tid] : 0;
    sh[tid] = v;
    __syncthreads();
    for (int off = 1; off < 256; off <<= 1) {
        int t = (tid >= off) ? sh[tid - off] : 0;
        __syncthreads();
        sh[tid] += t;
        __syncthreads();
    }
    if (tid < nb) bsums[tid] = sh[tid] - v;
}

__global__ __launch_bounds__(256) void scan3_kernel(int* __restrict__ rowptr,
                                                    int* __restrict__ cursor,
                                                    const int* __restrict__ bsums, int n) {
    const int tid = threadIdx.x;
    const int base = blockIdx.x * 1024 + tid * 4;
    const int add = bsums[blockIdx.x];
#pragma unroll
    for (int j = 0; j < 4; ++j) {
        int idx = base + j;
        if (idx < n) { int r = rowptr[idx] + add; rowptr[idx] = r; cursor[idx] = r; }
    }
}

// ---------- bucket edges by dst ----------
__global__ __launch_bounds__(256) void fill_kernel(const int* __restrict__ src,
                                                   const int* __restrict__ dst,
                                                   int* __restrict__ cursor,
                                                   int* __restrict__ sorted_src, int E) {
    int e = blockIdx.x * 256 + threadIdx.x;
    if (e < E) {
        int pos = atomicAdd(&cursor[dst[e]], 1);
        sorted_src[pos] = src[e];
    }
}

// ---------- gather-reduce: one wave (64 lanes) per dst row ----------
__global__ __launch_bounds__(256) void agg_kernel(const float* __restrict__ h,
                                                  const float* __restrict__ norm,
                                                  const int* __restrict__ rowptr,
                                                  const int* __restrict__ sorted_src,
                                                  float* __restrict__ agg, int n, int E) {
    const int wid = (blockIdx.x * 256 + threadIdx.x) >> 6;
    const int lane = threadIdx.x & 63;
    if (wid >= n) return;
    const int start = rowptr[wid];
    const int end = (wid + 1 < n) ? rowptr[wid + 1] : E;

    float ax = 0.f, ay = 0.f;
    const float* hp = h + lane * 2;
    int k = start;
    for (; k + 3 < end; k += 4) {
        int s0 = sorted_src[k], s1 = sorted_src[k + 1];
        int s2 = sorted_src[k + 2], s3 = sorted_src[k + 3];
        float n0 = norm[s0], n1 = norm[s1], n2 = norm[s2], n3 = norm[s3];
        float2 v0 = *(const float2*)(hp + (size_t)s0 * IN_DIM);
        float2 v1 = *(const float2*)(hp + (size_t)s1 * IN_DIM);
        float2 v2 = *(const float2*)(hp + (size_t)s2 * IN_DIM);
        float2 v3 = *(const float2*)(hp + (size_t)s3 * IN_DIM);
        ax += v0.x * n0 + v1.x * n1 + v2.x * n2 + v3.x * n3;
        ay += v0.y * n0 + v1.y * n1 + v2.y * n2 + v3.y * n3;
    }
    for (; k < end; ++k) {
        int s0 = sorted_src[k];
        float n0 = norm[s0];
        float2 v0 = *(const float2*)(hp + (size_t)s0 * IN_DIM);
        ax += v0.x * n0;
        ay += v0.y * n0;
    }
    const float nd = norm[wid];
    float2 o = make_float2(ax * nd, ay * nd);
    *(float2*)(agg + (size_t)wid * IN_DIM + lane * 2) = o;
}

// ---------- GEMM + row L2-normalize, register-blocked 2 rows x 8 cols ----------
// agg and out alias: all reads happen during tile staging before syncthreads;
// each row is written only by the block that owns it.
__global__ __launch_bounds__(256) void gemm_kernel(const float* __restrict__ h,
                                                   const float* agg,
                                                   const float* __restrict__ W,
                                                   const float* __restrict__ bias,
                                                   float* out, int n) {
    __shared__ float cat[ROWS * LDC];
    const int tid = threadIdx.x;
    const int row0 = blockIdx.x * ROWS;

    // Stage 32 rows x 256 floats = 2048 float4 slots; 8 per thread.
#pragma unroll
    for (int i = 0; i < 8; ++i) {
        int f = tid + i * 256;
        int r = f >> 6;
        int c4 = f & 63;
        int row = row0 + r;
        if (row < n) {
            float4 v;
            if (c4 < 32) v = *(const float4*)(h + (size_t)row * IN_DIM + c4 * 4);
            else         v = *(const float4*)(agg + (size_t)row * IN_DIM + (c4 - 32) * 4);
            *(float4*)(cat + r * LDC + c4 * 4) = v;
        }
    }
    __syncthreads();

    const int rg = tid >> 4;           // 0..15 -> rows rg*2, rg*2+1
    const int jg = (tid & 15) * 8;     // output col base
    const int r0 = rg * 2;
    const int row = row0 + r0;
    if (row >= n) return;

    float acc0[8], acc1[8];
#pragma unroll
    for (int i = 0; i < 8; ++i) { acc0[i] = 0.f; acc1[i] = 0.f; }

    const float* crow0 = cat + r0 * LDC;
    const float* crow1 = crow0 + LDC;
    const bool row1_ok = (row + 1 < n);

    for (int k = 0; k < 2 * IN_DIM; k += 4) {
        float4 a0 = *(const float4*)(crow0 + k);
        float4 a1 = *(const float4*)(crow1 + k);
        const float* wk = W + (size_t)k * HID + jg;
#pragma unroll
        for (int kk = 0; kk < 4; ++kk) {
            float4 w0 = *(const float4*)(wk + kk * HID);
            float4 w1 = *(const float4*)(wk + kk * HID + 4);
            float av0 = (&a0.x)[kk];
            float av1 = (&a1.x)[kk];
            acc0[0] += av0 * w0.x; acc0[1] += av0 * w0.y;
            acc0[2] += av0 * w0.z; acc0[3] += av0 * w0.w;
            acc0[4] += av0 * w1.x; acc0[5] += av0 * w1.y;
            acc0[6] += av0 * w1.z; acc0[7] += av0 * w1.w;
            acc1[0] += av1 * w0.x; acc1[1] += av1 * w0.y;
            acc1[2] += av1 * w0.z; acc1[3] += av1 * w0.w;
            acc1[4] += av1 * w1.x; acc1[5] += av1 * w1.y;
            acc1[6] += av1 * w1.z; acc1[7] += av1 * w1.w;
        }
    }

    float4 b0 = *(const float4*)(bias + jg);
    float4 b1 = *(const float4*)(bias + jg + 4);
    acc0[0] += b0.x; acc0[1] += b0.y; acc0[2] += b0.z; acc0[3] += b0.w;
    acc0[4] += b1.x; acc0[5] += b1.y; acc0[6] += b1.z; acc0[7] += b1.w;
    acc1[0] += b0.x; acc1[1] += b0.y; acc1[2] += b0.z; acc1[3] += b0.w;
    acc1[4] += b1.x; acc1[5] += b1.y; acc1[6] += b1.z; acc1[7] += b1.w;

    float ss0 = 0.f, ss1 = 0.f;
#pragma unroll
    for (int i = 0; i < 8; ++i) { ss0 += acc0[i] * acc0[i]; ss1 += acc1[i] * acc1[i]; }
    // 16 lanes (same rg, consecutive) own one row pair -> xor-reduce over 16
#pragma unroll
    for (int m = 1; m < 16; m <<= 1) {
        ss0 += __shfl_xor(ss0, m);
        ss1 += __shfl_xor(ss1, m);
    }
    float inv0 = rsqrtf(ss0);
    float inv1 = rsqrtf(ss1);

    float* orow0 = out + (size_t)row * HID + jg;
    *(float4*)orow0       = make_float4(acc0[0] * inv0, acc0[1] * inv0, acc0[2] * inv0, acc0[3] * inv0);
    *(float4*)(orow0 + 4) = make_float4(acc0[4] * inv0, acc0[5] * inv0, acc0[6] * inv0, acc0[7] * inv0);
    if (row1_ok) {
        float* orow1 = orow0 + HID;
        *(float4*)orow1       = make_float4(acc1[0] * inv1, acc1[1] * inv1, acc1[2] * inv1, acc1[3] * inv1);
        *(float4*)(orow1 + 4) = make_float4(acc1[4] * inv1, acc1[5] * inv1, acc1[6] * inv1, acc1[7] * inv1);
    }
}

extern "C" void kernel_launch(void* const* d_in, const int* in_sizes, int n_in,
                              void* d_out, int out_size, void* d_ws, size_t ws_size,
                              hipStream_t stream) {
    const float* h = (const float*)d_in[0];
    const float* W = (const float*)d_in[1];
    const float* bias = (const float*)d_in[2];
    const int* src = (const int*)d_in[3];
    const int* dst = (const int*)d_in[4];
    float* out = (float*)d_out;

    const int n = in_sizes[0] / IN_DIM;   // 100000
    const int E = in_sizes[3];            // 1600000

    // ws: deg[N] | rowptr[N] | cursor[N] | norm[N] | bsums[256] | sorted_src[E]
    int* deg = (int*)d_ws;
    int* rowptr = deg + n;
    int* cursor = rowptr + n;
    float* norm = (float*)(cursor + n);
    int* bsums = (int*)(norm + n);
    int* sorted_src = bsums + 256;

    const int nb = (n + 1023) / 1024;

    hipMemsetAsync(deg, 0, (size_t)n * sizeof(int), stream);

    deg_kernel<<<(E + 255) / 256, 256, 0, stream>>>(dst, deg, E);
    norm_kernel<<<(n + 255) / 256, 256, 0, stream>>>(deg, norm, n);

    scan1_kernel<<<nb, 256, 0, stream>>>(deg, rowptr, bsums, n);
    scan2_kernel<<<1, 256, 0, stream>>>(bsums, nb);
    scan3_kernel<<<nb, 256, 0, stream>>>(rowptr, cursor, bsums, n);

    fill_kernel<<<(E + 255) / 256, 256, 0, stream>>>(src, dst, cursor, sorted_src, E);

    agg_kernel<<<(n + 3) / 4, 256, 0, stream>>>(h, norm, rowptr, sorted_src, out, n, E);

    gemm_kernel<<<(n + ROWS - 1) / ROWS, 256, 0, stream>>>(h, out, W, bias, out, n);
}

// Round 4
// 355.281 us; speedup vs baseline: 8.9057x; 1.4957x over previous
//
#include <hip/hip_runtime.h>

#define IN_DIM 128
#define HID 128

typedef __attribute__((ext_vector_type(8))) short short8;
typedef __attribute__((ext_vector_type(4))) float f32x4;

__device__ __forceinline__ unsigned short f2bf(float f) {
    union { float f; unsigned u; } a; a.f = f;
    unsigned r = a.u + 0x7fffu + ((a.u >> 16) & 1u);
    return (unsigned short)(r >> 16);
}

// ---------- degree count ----------
__global__ __launch_bounds__(256) void deg_kernel(const int* __restrict__ dst,
                                                  int* __restrict__ deg, int E) {
    int e = blockIdx.x * 256 + threadIdx.x;
    if (e < E) atomicAdd(&deg[dst[e]], 1);
}

// ---------- exclusive scan of deg -> rowptr; also emits norm ----------
__global__ __launch_bounds__(256) void scan1_kernel(const int* __restrict__ deg,
                                                    int* __restrict__ excl,
                                                    int* __restrict__ bsums,
                                                    float* __restrict__ norm, int n) {
    __shared__ int sh[256];
    const int tid = threadIdx.x;
    const int base = blockIdx.x * 1024 + tid * 4;
    int v[4];
#pragma unroll
    for (int j = 0; j < 4; ++j) {
        int idx = base + j;
        v[j] = (idx < n) ? deg[idx] : 0;
        if (idx < n) norm[idx] = rsqrtf(fmaxf((float)v[j], 1.0f));
    }
    int sum = v[0] + v[1] + v[2] + v[3];
    sh[tid] = sum;
    __syncthreads();
    for (int off = 1; off < 256; off <<= 1) {
        int t = (tid >= off) ? sh[tid - off] : 0;
        __syncthreads();
        sh[tid] += t;
        __syncthreads();
    }
    int run = sh[tid] - sum;
#pragma unroll
    for (int j = 0; j < 4; ++j) { int idx = base + j; if (idx < n) excl[idx] = run; run += v[j]; }
    if (tid == 255) bsums[blockIdx.x] = sh[255];
}

__global__ __launch_bounds__(256) void scan2_kernel(int* __restrict__ bsums, int nb) {
    __shared__ int sh[256];
    const int tid = threadIdx.x;
    int v = (tid < nb) ? bsums[tid] : 0;
    sh[tid] = v;
    __syncthreads();
    for (int off = 1; off < 256; off <<= 1) {
        int t = (tid >= off) ? sh[tid - off] : 0;
        __syncthreads();
        sh[tid] += t;
        __syncthreads();
    }
    if (tid < nb) bsums[tid] = sh[tid] - v;
}

__global__ __launch_bounds__(256) void scan3_kernel(int* __restrict__ rowptr,
                                                    int* __restrict__ cursor,
                                                    const int* __restrict__ bsums, int n) {
    const int tid = threadIdx.x;
    const int base = blockIdx.x * 1024 + tid * 4;
    const int add = bsums[blockIdx.x];
#pragma unroll
    for (int j = 0; j < 4; ++j) {
        int idx = base + j;
        if (idx < n) { int r = rowptr[idx] + add; rowptr[idx] = r; cursor[idx] = r; }
    }
}

// ---------- bucket edges by dst ----------
__global__ __launch_bounds__(256) void fill_kernel(const int* __restrict__ src,
                                                   const int* __restrict__ dst,
                                                   int* __restrict__ cursor,
                                                   int* __restrict__ sorted_src, int E) {
    int e = blockIdx.x * 256 + threadIdx.x;
    if (e < E) {
        int pos = atomicAdd(&cursor[dst[e]], 1);
        sorted_src[pos] = src[e];
    }
}

// ---------- gather-reduce: one wave per dst row ----------
__global__ __launch_bounds__(256) void agg_kernel(const float* __restrict__ h,
                                                  const float* __restrict__ norm,
                                                  const int* __restrict__ rowptr,
                                                  const int* __restrict__ sorted_src,
                                                  float* __restrict__ agg, int n, int E) {
    const int wid = (blockIdx.x * 256 + threadIdx.x) >> 6;
    const int lane = threadIdx.x & 63;
    if (wid >= n) return;
    const int start = rowptr[wid];
    const int end = (wid + 1 < n) ? rowptr[wid + 1] : E;

    float ax = 0.f, ay = 0.f;
    const float* hp = h + lane * 2;
    int k = start;
    for (; k + 7 < end; k += 8) {
        int s[8];
#pragma unroll
        for (int u = 0; u < 8; ++u) s[u] = sorted_src[k + u];
        float nn[8];
#pragma unroll
        for (int u = 0; u < 8; ++u) nn[u] = norm[s[u]];
        float2 v[8];
#pragma unroll
        for (int u = 0; u < 8; ++u) v[u] = *(const float2*)(hp + (size_t)s[u] * IN_DIM);
#pragma unroll
        for (int u = 0; u < 8; ++u) { ax += v[u].x * nn[u]; ay += v[u].y * nn[u]; }
    }
    for (; k < end; ++k) {
        int s0 = sorted_src[k];
        float n0 = norm[s0];
        float2 v0 = *(const float2*)(hp + (size_t)s0 * IN_DIM);
        ax += v0.x * n0;
        ay += v0.y * n0;
    }
    const float nd = norm[wid];
    float2 o = make_float2(ax * nd, ay * nd);
    *(float2*)(agg + (size_t)wid * IN_DIM + lane * 2) = o;
}

// ---------- pre-pack W into MFMA B-fragment lane order (bf16) ----------
// fragment (kc,nt): lane l, elem j -> W[kc*32 + (l>>4)*8 + j][nt*16 + (l&15)]
__global__ __launch_bounds__(256) void packW_kernel(const float* __restrict__ W,
                                                    unsigned short* __restrict__ pw) {
    int t = blockIdx.x * 256 + threadIdx.x;  // 0..4095
    int lane = t & 63;
    int frag = t >> 6;                        // kc*8 + nt
    int kc = frag >> 3, nt = frag & 7;
    int k0 = kc * 32 + (lane >> 4) * 8;
    int col = nt * 16 + (lane & 15);
    unsigned short o[8];
#pragma unroll
    for (int j = 0; j < 8; ++j) o[j] = f2bf(W[(size_t)(k0 + j) * HID + col]);
    short8 v;
#pragma unroll
    for (int j = 0; j < 8; ++j) v[j] = (short)o[j];
    *(short8*)(pw + (size_t)t * 8) = v;
}

// ---------- MFMA GEMM + bias + row L2-normalize ----------
// Block = 64 rows, 4 waves; wave w owns rows [blk*64 + w*16, +16), all 128 cols.
// A-frags from h (kc<4) / agg (kc>=4, == out, wave-local in-place). No LDS.
__global__ __launch_bounds__(256) void gemm_kernel(const float* __restrict__ h,
                                                   const float* agg,
                                                   const unsigned short* __restrict__ pw,
                                                   const float* __restrict__ bias,
                                                   float* out, int n) {
    const int tid = threadIdx.x;
    const int wave = tid >> 6;
    const int lane = tid & 63;
    const int l15 = lane & 15;
    const int lg = lane >> 4;                 // 0..3
    const int rowBase = blockIdx.x * 64 + wave * 16;
    const int arow = min(rowBase + l15, n - 1);   // A-load row (clamped)

    f32x4 acc[8];
#pragma unroll
    for (int nt = 0; nt < 8; ++nt) acc[nt] = (f32x4){0.f, 0.f, 0.f, 0.f};

#pragma unroll
    for (int kc = 0; kc < 8; ++kc) {
        const int k = kc * 32 + lg * 8;
        const float* ap = (kc < 4) ? (h + (size_t)arow * IN_DIM + k)
                                   : (agg + (size_t)arow * IN_DIM + (k - 128));
        float4 a0 = *(const float4*)ap;
        float4 a1 = *(const float4*)(ap + 4);
        short8 af;
        af[0] = (short)f2bf(a0.x); af[1] = (short)f2bf(a0.y);
        af[2] = (short)f2bf(a0.z); af[3] = (short)f2bf(a0.w);
        af[4] = (short)f2bf(a1.x); af[5] = (short)f2bf(a1.y);
        af[6] = (short)f2bf(a1.z); af[7] = (short)f2bf(a1.w);
        const unsigned short* bp = pw + ((size_t)(kc * 8) * 64 + lane) * 8;
#pragma unroll
        for (int nt = 0; nt < 8; ++nt) {
            short8 bf = *(const short8*)(bp + (size_t)nt * 64 * 8);
            acc[nt] = __builtin_amdgcn_mfma_f32_16x16x32_bf16(af, bf, acc[nt], 0, 0, 0);
        }
    }

    // C layout: col = nt*16 + l15, row = rowBase + lg*4 + j
    float ss[4] = {0.f, 0.f, 0.f, 0.f};
#pragma unroll
    for (int nt = 0; nt < 8; ++nt) {
        float b = bias[nt * 16 + l15];
#pragma unroll
        for (int j = 0; j < 4; ++j) {
            float y = acc[nt][j] + b;
            acc[nt][j] = y;
            ss[j] += y * y;
        }
    }
#pragma unroll
    for (int m = 1; m < 16; m <<= 1) {
#pragma unroll
        for (int j = 0; j < 4; ++j) ss[j] += __shfl_xor(ss[j], m);
    }
#pragma unroll
    for (int j = 0; j < 4; ++j) {
        const int r = rowBase + lg * 4 + j;
        if (r < n) {
            const float inv = rsqrtf(ss[j]);
            float* op = out + (size_t)r * HID + l15;
#pragma unroll
            for (int nt = 0; nt < 8; ++nt) op[nt * 16] = acc[nt][j] * inv;
        }
    }
}

extern "C" void kernel_launch(void* const* d_in, const int* in_sizes, int n_in,
                              void* d_out, int out_size, void* d_ws, size_t ws_size,
                              hipStream_t stream) {
    const float* h = (const float*)d_in[0];
    const float* W = (const float*)d_in[1];
    const float* bias = (const float*)d_in[2];
    const int* src = (const int*)d_in[3];
    const int* dst = (const int*)d_in[4];
    float* out = (float*)d_out;

    const int n = in_sizes[0] / IN_DIM;   // 100000
    const int E = in_sizes[3];            // 1600000

    // ws: deg[N] | rowptr[N] | cursor[N] | norm[N] | bsums[256] | sorted_src[E] | packedW[32K ushort]
    int* deg = (int*)d_ws;
    int* rowptr = deg + n;
    int* cursor = rowptr + n;
    float* norm = (float*)(cursor + n);
    int* bsums = (int*)(norm + n);
    int* sorted_src = bsums + 256;
    unsigned short* pw = (unsigned short*)(sorted_src + E);

    const int nb = (n + 1023) / 1024;

    hipMemsetAsync(deg, 0, (size_t)n * sizeof(int), stream);

    packW_kernel<<<16, 256, 0, stream>>>(W, pw);
    deg_kernel<<<(E + 255) / 256, 256, 0, stream>>>(dst, deg, E);

    scan1_kernel<<<nb, 256, 0, stream>>>(deg, rowptr, bsums, norm, n);
    scan2_kernel<<<1, 256, 0, stream>>>(bsums, nb);
    scan3_kernel<<<nb, 256, 0, stream>>>(rowptr, cursor, bsums, n);

    fill_kernel<<<(E + 255) / 256, 256, 0, stream>>>(src, dst, cursor, sorted_src, E);

    agg_kernel<<<(n + 3) / 4, 256, 0, stream>>>(h, norm, rowptr, sorted_src, out, n, E);

    gemm_kernel<<<(n + 63) / 64, 256, 0, stream>>>(h, out, pw, bias, out, n);
}